// Round 5
// baseline (210.886 us; speedup 1.0000x reference)
//
#include <hip/hip_runtime.h>
#include <hip/hip_bf16.h>
#include <stdint.h>

#define Ss 2048
#define Dd 64
#define NBH 64     // B*H
#define NQT 32     // 64-row q-tiles

using f32x16 = __attribute__((ext_vector_type(16))) float;
using s16x8  = __attribute__((ext_vector_type(8))) short;

#if __has_builtin(__builtin_amdgcn_exp2f)
#define EXP2(x) __builtin_amdgcn_exp2f(x)
#else
#define EXP2(x) exp2f(x)
#endif

__device__ __forceinline__ uint32_t cvt_pk_bf16(float lo, float hi) {
    uint32_t r;
    asm("v_cvt_pk_bf16_f32 %0, %1, %2" : "=v"(r) : "v"(lo), "v"(hi));
    return r;
}

// HW half-swap: a := {a_lo, b_lo}, b := {a_hi, b_hi}
__device__ __forceinline__ void pls(uint32_t& a, uint32_t& b) {
#if __has_builtin(__builtin_amdgcn_permlane32_swap)
    auto r = __builtin_amdgcn_permlane32_swap(a, b, false, false);
    a = r[0]; b = r[1];
#else
    asm("v_permlane32_swap_b32 %0, %1" : "+v"(a), "+v"(b));
#endif
}
__device__ __forceinline__ float xhalf_max(float x) {
    union { float f; uint32_t u; } a, b;
    a.f = x; b.f = x;
    pls(a.u, b.u);
    return fmaxf(a.f, b.f);
}
__device__ __forceinline__ float xhalf_add(float x) {
    union { float f; uint32_t u; } a, b;
    a.f = x; b.f = x;
    pls(a.u, b.u);
    return a.f + b.f;
}

// ---------------- fused prepass: K fp32->bf16 (same layout) + V -> V^T bf16 [bh][d][kv] ----------------
__global__ __launch_bounds__(256)
void prep_kv(const float* __restrict__ K, const float* __restrict__ V,
             uint16_t* __restrict__ Kb, uint16_t* __restrict__ Vt) {
    const int bh  = blockIdx.y;
    const int kv0 = blockIdx.x * 64;
    __shared__ float ts[64][65];
    const size_t off = (size_t)bh * Ss * Dd + (size_t)kv0 * Dd;

    // K convert: thread r=tid>>2 handles 16 cols
    {
        const int r = threadIdx.x >> 2;
        const int c = (threadIdx.x & 3) * 16;
        const float* kp = K + off + (size_t)r * Dd + c;
        const float4 a  = *(const float4*)(kp);
        const float4 b  = *(const float4*)(kp + 4);
        const float4 c4 = *(const float4*)(kp + 8);
        const float4 d4 = *(const float4*)(kp + 12);
        union { uint32_t u[8]; struct { s16x8 a, b; } s; } o;
        o.u[0] = cvt_pk_bf16(a.x, a.y);   o.u[1] = cvt_pk_bf16(a.z, a.w);
        o.u[2] = cvt_pk_bf16(b.x, b.y);   o.u[3] = cvt_pk_bf16(b.z, b.w);
        o.u[4] = cvt_pk_bf16(c4.x, c4.y); o.u[5] = cvt_pk_bf16(c4.z, c4.w);
        o.u[6] = cvt_pk_bf16(d4.x, d4.y); o.u[7] = cvt_pk_bf16(d4.z, d4.w);
        uint16_t* op = Kb + off + (size_t)r * Dd + c;
        *(s16x8*)op       = o.s.a;
        *(s16x8*)(op + 8) = o.s.b;
    }

    // V transpose via LDS bounce
    const float* vp = V + off;
    {
        const int r = threadIdx.x >> 2;
        const int c = (threadIdx.x & 3) * 16;
        #pragma unroll
        for (int j = 0; j < 4; ++j)
            *(float4*)&ts[r][c + 4*j] = *(const float4*)(vp + (size_t)r * Dd + c + 4*j);
    }
    __syncthreads();
    {
        const int d   = threadIdx.x >> 2;
        const int k16 = (threadIdx.x & 3) * 16;
        union { uint32_t u[8]; struct { s16x8 a, b; } s; } o;
        #pragma unroll
        for (int j = 0; j < 8; ++j)
            o.u[j] = cvt_pk_bf16(ts[k16 + 2*j][d], ts[k16 + 2*j + 1][d]);
        uint16_t* op = Vt + ((size_t)bh * Dd + d) * Ss + kv0 + k16;
        *(s16x8*)op       = o.s.a;
        *(s16x8*)(op + 8) = o.s.b;
    }
}

// ---------------- main: paired causal blocks, 2 waves x 32 q-rows, triple-buffered counted-vmcnt pipeline ----------------
__global__ __launch_bounds__(128, 2)
void attn_fwd_main(const float* __restrict__ Qg, const uint16_t* __restrict__ Kb,
                   const uint16_t* __restrict__ Vt, float* __restrict__ Og) {
    const int qbp = blockIdx.x;          // pair 0..15 -> q-tiles {31-qbp, qbp}
    const int bh  = blockIdx.y;
    const int tid = threadIdx.x;
    const int w   = tid >> 6;            // 0..1
    const int l   = tid & 63;
    const int l31 = l & 31;
    const int hi  = l >> 5;

    __shared__ char smem[3 * 16384];     // 3 x (K 8KB + V 8KB); epilogue aliases

    const float* Qp = Qg + (size_t)bh * Ss * Dd;
    const char*  Kp = (const char*)(Kb + (size_t)bh * Ss * Dd);
    const char*  Vp = (const char*)(Vt + (size_t)bh * Dd * Ss);
    float*       Op = Og + (size_t)bh * Ss * Dd;

    const int rK = l >> 3;               // row within 8-row chunk
    const int bX = (l & 7) ^ rK;         // inverse-swizzled 16B slot

    const float SCALE = 0.18033688011112042f;  // (1/sqrt(64)) * log2(e)

    for (int half = 0; half < 2; ++half) {
        const int qt   = half ? qbp : (NQT - 1 - qbp);
        const int q0   = qt * 64;
        const int qmin = q0 + 32 * w;
        const int qrow = qmin + l31;
        const int nt   = qt + 1;

        // ---- Q fragments (B-operand of swapped QK^T) ----
        s16x8 qf[4];
        {
            const float* qp = Qp + (size_t)qrow * Dd;
            #pragma unroll
            for (int kt = 0; kt < 4; ++kt) {
                const float4 a = *(const float4*)(qp + kt*16 + hi*8);
                const float4 b = *(const float4*)(qp + kt*16 + hi*8 + 4);
                union { uint32_t u[4]; s16x8 v; } q;
                q.u[0] = cvt_pk_bf16(a.x*SCALE, a.y*SCALE);
                q.u[1] = cvt_pk_bf16(a.z*SCALE, a.w*SCALE);
                q.u[2] = cvt_pk_bf16(b.x*SCALE, b.y*SCALE);
                q.u[3] = cvt_pk_bf16(b.z*SCALE, b.w*SCALE);
                qf[kt] = q.v;
            }
        }

        f32x16 acc[2];
        #pragma unroll
        for (int c = 0; c < 2; ++c)
            #pragma unroll
            for (int r = 0; r < 16; ++r) acc[c][r] = 0.f;
        float mrun = -1e30f, lrun = 0.f;

        auto STAGE = [&](int t, int buf) {
            char* Kd = smem + buf * 16384;
            char* Vd = Kd + 8192;
            #pragma unroll
            for (int c2 = 0; c2 < 4; ++c2) {
                const int c = 4 * w + c2;                         // chunk 0..7
                const char* gk = Kp + (size_t)(t*64 + c*8 + rK) * 128 + bX * 16;
                const char* gv = Vp + (size_t)(c*8 + rK) * (Ss*2) + t*128 + bX * 16;
#if __has_builtin(__builtin_amdgcn_global_load_lds)
                __builtin_amdgcn_global_load_lds((const uint32_t*)gk, (uint32_t*)(Kd + c*1024), 16, 0, 0);
                __builtin_amdgcn_global_load_lds((const uint32_t*)gv, (uint32_t*)(Vd + c*1024), 16, 0, 0);
#else
                *(s16x8*)(Kd + c*1024 + l*16) = *(const s16x8*)gk;
                *(s16x8*)(Vd + c*1024 + l*16) = *(const s16x8*)gv;
#endif
            }
        };

        __syncthreads();                 // protect smem (prev half epilogue) before restaging
        STAGE(0, 0);                     // 8 loads/wave in flight
        if (nt > 1) STAGE(1, 1);         // 16 in flight
        int ic  = 0;                     // compute buffer  = t % 3
        int ic2 = 2;                     // stage buffer    = (t+2) % 3

        for (int t = 0; t < nt; ++t) {
            // drain ONLY tile t's loads (8 newer may stay in flight), then publish
            if (t + 1 < nt) { asm volatile("s_waitcnt vmcnt(8)" ::: "memory"); }
            else            { asm volatile("s_waitcnt vmcnt(0)" ::: "memory"); }
            __builtin_amdgcn_s_barrier();
            // issue depth-2 prefetch AFTER the barrier (all waves done reading this buffer)
            if (t + 2 < nt) STAGE(t + 2, ic2);

            const int kv0 = t * 64;
            const char* Kd = smem + ic * 16384;
            const char* Vd = Kd + 8192;

            // ---- S^T = K @ Q^T (log2 domain) ----
            f32x16 st[2];
            __builtin_amdgcn_s_setprio(1);
            #pragma unroll
            for (int t2 = 0; t2 < 2; ++t2) {
                #pragma unroll
                for (int r = 0; r < 16; ++r) st[t2][r] = 0.f;
                const int kvr = t2 * 32 + l31;
                const int sw  = (kvr & 7) << 4;
                #pragma unroll
                for (int kt = 0; kt < 4; ++kt) {
                    const s16x8 kf = *(const s16x8*)(Kd + ((kvr*128 + kt*32 + hi*16) ^ sw));
                    st[t2] = __builtin_amdgcn_mfma_f32_32x32x16_bf16(kf, qf[kt], st[t2], 0, 0, 0);
                }
            }
            __builtin_amdgcn_s_setprio(0);

            // ---- causal mask (diagonal tile only) ----
            if (kv0 + 63 > qmin) {
                #pragma unroll
                for (int t2 = 0; t2 < 2; ++t2)
                    #pragma unroll
                    for (int r = 0; r < 16; ++r) {
                        const int kvloc = 32*t2 + (r & 3) + 8*(r >> 2) + 4*hi;
                        if (kv0 + kvloc > qrow) st[t2][r] = -1e30f;
                    }
            }

            // ---- online softmax (permlane cross-half, no LDS ops) ----
            float mx0 = st[0][0], mx1 = st[0][1], mx2 = st[0][2], mx3 = st[0][3];
            #pragma unroll
            for (int t2 = 0; t2 < 2; ++t2)
                #pragma unroll
                for (int r = (t2 ? 0 : 4); r < 16; r += 4) {
                    mx0 = fmaxf(mx0, st[t2][r+0]); mx1 = fmaxf(mx1, st[t2][r+1]);
                    mx2 = fmaxf(mx2, st[t2][r+2]); mx3 = fmaxf(mx3, st[t2][r+3]);
                }
            float pmax = fmaxf(fmaxf(mx0, mx1), fmaxf(mx2, mx3));
            pmax = xhalf_max(pmax);

            if (!__all(pmax - mrun <= 11.f)) {   // T13 defer-max (log2 THR)
                const float newm = fmaxf(mrun, pmax);
                const float corr = EXP2(mrun - newm);
                mrun = newm;
                lrun *= corr;
                acc[0] *= corr;
                acc[1] *= corr;
            }

            float ps0 = 0.f, ps1 = 0.f, ps2 = 0.f, ps3 = 0.f;
            #pragma unroll
            for (int t2 = 0; t2 < 2; ++t2)
                #pragma unroll
                for (int r = 0; r < 16; r += 4) {
                    const float p0 = EXP2(st[t2][r+0] - mrun);
                    const float p1 = EXP2(st[t2][r+1] - mrun);
                    const float p2 = EXP2(st[t2][r+2] - mrun);
                    const float p3 = EXP2(st[t2][r+3] - mrun);
                    st[t2][r+0] = p0; st[t2][r+1] = p1;
                    st[t2][r+2] = p2; st[t2][r+3] = p3;
                    ps0 += p0; ps1 += p1; ps2 += p2; ps3 += p3;
                }
            lrun += xhalf_add((ps0 + ps1) + (ps2 + ps3));

            // ---- P -> bf16 + permlane32_swap, feed PV ----
            __builtin_amdgcn_s_setprio(1);
            #pragma unroll
            for (int kt = 0; kt < 4; ++kt) {
                const int t2 = kt >> 1, base = (kt & 1) * 8;
                uint32_t u0 = cvt_pk_bf16(st[t2][base+0], st[t2][base+1]);
                uint32_t u2 = cvt_pk_bf16(st[t2][base+4], st[t2][base+5]);
                uint32_t u1 = cvt_pk_bf16(st[t2][base+2], st[t2][base+3]);
                uint32_t u3 = cvt_pk_bf16(st[t2][base+6], st[t2][base+7]);
                pls(u0, u2);
                pls(u1, u3);
                union { uint32_t u[4]; s16x8 v; } pa;
                pa.u[0] = u0; pa.u[1] = u1; pa.u[2] = u2; pa.u[3] = u3;
                #pragma unroll
                for (int c = 0; c < 2; ++c) {
                    const int d = 32*c + l31;
                    const s16x8 vf = *(const s16x8*)(Vd + ((d*128 + kt*32 + hi*16) ^ ((d & 7) << 4)));
                    acc[c] = __builtin_amdgcn_mfma_f32_32x32x16_bf16(vf, pa.v, acc[c], 0, 0, 0);
                }
            }
            __builtin_amdgcn_s_setprio(0);

            ic  = (ic  == 2) ? 0 : ic  + 1;
            ic2 = (ic2 == 2) ? 0 : ic2 + 1;
        }

        __syncthreads();                 // all waves done with K/V LDS before ob overwrite

        // ---- epilogue: O^T -> O via padded LDS bounce ----
        float (*ob)[68] = (float(*)[68])smem;
        const float inv = 1.0f / lrun;
        {
            const int qloc = 32*w + l31;
            #pragma unroll
            for (int c = 0; c < 2; ++c)
                #pragma unroll
                for (int r = 0; r < 16; ++r) {
                    const int d = 32*c + (r & 3) + 8*(r >> 2) + 4*hi;
                    ob[qloc][d] = acc[c][r] * inv;
                }
        }
        __syncthreads();
        #pragma unroll
        for (int i = 0; i < 8; ++i) {
            const int idx = i*128 + tid;
            const int row = idx >> 4;
            const int c4  = (idx & 15) * 4;
            const float4 v = *(const float4*)&ob[row][c4];
            *(float4*)(Op + (size_t)(q0 + row) * Dd + c4) = v;
        }
        // loop-top __syncthreads protects smem before next half's staging
    }
}

extern "C" void kernel_launch(void* const* d_in, const int* in_sizes, int n_in,
                              void* d_out, int out_size, void* d_ws, size_t ws_size,
                              hipStream_t stream) {
    const float* Q = (const float*)d_in[0];
    const float* K = (const float*)d_in[1];
    const float* V = (const float*)d_in[2];
    float* O = (float*)d_out;
    const size_t nelem = (size_t)NBH * Ss * Dd;           // 8388608

    uint16_t* Kb = (uint16_t*)d_ws;
    uint16_t* Vt = Kb + nelem;
    prep_kv<<<dim3(Ss / 64, NBH), 256, 0, stream>>>(K, V, Kb, Vt);
    attn_fwd_main<<<dim3(NQT / 2, NBH), 128, 0, stream>>>(Q, Kb, Vt, O);
}